// Round 1
// baseline (319.417 us; speedup 1.0000x reference)
//
#include <hip/hip_runtime.h>
#include <math.h>

// Problem constants
constexpr int BS  = 8;
constexpr int NS  = 2048;
constexpr int NCP = 8;
constexpr int NH  = 8;
constexpr int C   = 128;
constexpr int HID = 128;
constexpr int RR  = 128;   // plane resolution R

// ---------------------------------------------------------------------------
// Transpose planes (B, C, R, R) -> [pl][b][y][x][c] so channel reads coalesce.
// Treated per (plane, batch) as a (C x R*R) -> (R*R x C) 2D transpose.
// ---------------------------------------------------------------------------
__global__ __launch_bounds__(256) void transpose_k(
    const float* __restrict__ pxz, const float* __restrict__ pxy,
    const float* __restrict__ pyz, float* __restrict__ dst)
{
    const int z  = blockIdx.z;          // z = pl*8 + b
    const int pl = z >> 3;
    const int b  = z & 7;
    const float* src = (pl == 0 ? pxz : (pl == 1 ? pxy : pyz)) + (size_t)b * C * RR * RR;
    float* d = dst + (size_t)z * (RR * RR * C);

    __shared__ float tile[32][33];
    const int N  = RR * RR;             // 16384
    const int n0 = blockIdx.x * 32;
    const int m0 = blockIdx.y * 32;
    const int tx = threadIdx.x, ty = threadIdx.y;

    #pragma unroll
    for (int ii = 0; ii < 4; ++ii) {
        int m = m0 + ty + ii * 8;
        tile[ty + ii * 8][tx] = src[(size_t)m * N + n0 + tx];
    }
    __syncthreads();
    #pragma unroll
    for (int ii = 0; ii < 4; ++ii) {
        int n = n0 + ty + ii * 8;
        d[(size_t)n * C + m0 + tx] = tile[tx][ty + ii * 8];
    }
}

// ---------------------------------------------------------------------------
// Bilinear sample of one channel. TR: transposed layout [y][x][c] (coalesced),
// else original layout [c][y][x].
// ---------------------------------------------------------------------------
template <bool TR>
__device__ __forceinline__ float bilin(const float* __restrict__ pb,
                                       float u, float v, int c)
{
    float x = fminf(fmaxf(u, 0.f), 1.f) * (float)(RR - 1);
    float y = fminf(fmaxf(v, 0.f), 1.f) * (float)(RR - 1);
    float x0f = floorf(x), y0f = floorf(y);
    float wx = x - x0f, wy = y - y0f;
    int x0 = (int)x0f, y0 = (int)y0f;
    int x1 = min(x0 + 1, RR - 1);
    int y1 = min(y0 + 1, RR - 1);
    float f00, f01, f10, f11;
    if (TR) {
        f00 = pb[(size_t)(y0 * RR + x0) * C + c];
        f01 = pb[(size_t)(y0 * RR + x1) * C + c];
        f10 = pb[(size_t)(y1 * RR + x0) * C + c];
        f11 = pb[(size_t)(y1 * RR + x1) * C + c];
    } else {
        const float* pc = pb + (size_t)c * RR * RR;
        f00 = pc[y0 * RR + x0];
        f01 = pc[y0 * RR + x1];
        f10 = pc[y1 * RR + x0];
        f11 = pc[y1 * RR + x1];
    }
    return f00 * (1.f - wx) * (1.f - wy) + f01 * wx * (1.f - wy)
         + f10 * (1.f - wx) * wy        + f11 * wx * wy;
}

// ---------------------------------------------------------------------------
// Main kernel: one 128-thread block per query, thread = channel.
// ---------------------------------------------------------------------------
template <bool TR>
__global__ __launch_bounds__(128) void attn_k(
    const float* __restrict__ qpos,
    const float* __restrict__ pxz, const float* __restrict__ pxy,
    const float* __restrict__ pyz,
    const float* __restrict__ cpts,
    const float* __restrict__ Wv, const float* __restrict__ bv,
    const float* __restrict__ Ww, const float* __restrict__ bw,
    const float* __restrict__ Wo, const float* __restrict__ bo,
    float* __restrict__ out)
{
    const int q = blockIdx.x;       // 0 .. BS*NS-1
    const int b = q / NS;
    const int c = threadIdx.x;      // channel

    const float* qp = qpos + (size_t)q * 9;
    const float px = qp[0], py = qp[1], pz = qp[2];
    const float a1x = qp[3], a1y = qp[4], a1z = qp[5];
    const float a2x = qp[6], a2y = qp[7], a2z = qp[8];

    // rotation_6d_to_matrix (rows b1, b2, b3)
    float inv = 1.f / sqrtf(a1x * a1x + a1y * a1y + a1z * a1z);
    float b1x = a1x * inv, b1y = a1y * inv, b1z = a1z * inv;
    float dd  = b1x * a2x + b1y * a2y + b1z * a2z;
    float b2x = a2x - dd * b1x, b2y = a2y - dd * b1y, b2z = a2z - dd * b1z;
    inv = 1.f / sqrtf(b2x * b2x + b2y * b2y + b2z * b2z);
    b2x *= inv; b2y *= inv; b2z *= inv;
    float b3x = b1y * b2z - b1z * b2y;
    float b3y = b1z * b2x - b1x * b2z;
    float b3z = b1x * b2y - b1y * b2x;

    // positions: [0] = base query, [1..8] = anchors
    float posx[NCP + 1], posy[NCP + 1], posz[NCP + 1];
    posx[0] = px; posy[0] = py; posz[0] = pz;
    #pragma unroll
    for (int g = 0; g < NCP; ++g) {
        float cx = cpts[g * 3 + 0], cy = cpts[g * 3 + 1], cz = cpts[g * 3 + 2];
        posx[g + 1] = px + b1x * cx + b1y * cy + b1z * cz;
        posy[g + 1] = py + b2x * cx + b2y * cy + b2z * cz;
        posz[g + 1] = pz + b3x * cx + b3y * cy + b3z * cz;
    }

    const size_t pb_off = (size_t)b * C * RR * RR;   // same slab size both layouts
    const float* Pxz = pxz + pb_off;
    const float* Pxy = pxy + pb_off;
    const float* Pyz = pyz + pb_off;

    __shared__ float sFeat[C];
    __shared__ float sW[NCP * NH];
    __shared__ float sWs[NCP];
    __shared__ float sComb[C];
    __shared__ float sO1[HID];

    // base feature
    float feat = bilin<TR>(Pxz, posx[0], posz[0], c)
               + bilin<TR>(Pxy, posx[0], posy[0], c)
               + bilin<TR>(Pyz, posy[0], posz[0], c);
    sFeat[c] = feat;

    // anchor features
    float sf[NCP];
    #pragma unroll
    for (int g = 0; g < NCP; ++g) {
        sf[g] = bilin<TR>(Pxz, posx[g + 1], posz[g + 1], c)
              + bilin<TR>(Pxy, posx[g + 1], posy[g + 1], c)
              + bilin<TR>(Pyz, posy[g + 1], posz[g + 1], c);
    }
    __syncthreads();   // sFeat visible

    // w = feat @ W_w + b_w   (64 outputs, threads 0..63)
    if (c < NCP * NH) {
        float acc = bw[c];
        #pragma unroll 8
        for (int k = 0; k < C; ++k) acc += sFeat[k] * Ww[k * (NCP * NH) + c];
        sW[c] = acc;
    }
    __syncthreads();

    // ws[j] = sum_i w[i, j]  (collapse NCP index of w)
    if (c < NCP) {
        float acc = 0.f;
        #pragma unroll
        for (int i = 0; i < NCP; ++i) acc += sW[i * NH + c];
        sWs[c] = acc;
    }
    __syncthreads();

    // combine anchors: comb[c] = sum_g ws[g] * sf[g][c];  Ssum = sum_g ws[g]
    float Ssum = 0.f, comb = 0.f;
    #pragma unroll
    for (int g = 0; g < NCP; ++g) {
        float w = sWs[g];
        Ssum += w;
        comb += w * sf[g];
    }
    sComb[c] = comb;
    __syncthreads();

    // out1[k] = comb . W_v[:,k] + Ssum * b_v[k]
    float o1 = Ssum * bv[c];
    #pragma unroll 8
    for (int k = 0; k < C; ++k) o1 += sComb[k] * Wv[k * HID + c];
    sO1[c] = o1;
    __syncthreads();

    // out[m] = out1 . W_o[:,m] + b_o[m] + feat[m]
    float o2 = bo[c] + feat;
    #pragma unroll 8
    for (int k = 0; k < HID; ++k) o2 += sO1[k] * Wo[k * C + c];
    out[(size_t)q * C + c] = o2;
}

// ---------------------------------------------------------------------------
extern "C" void kernel_launch(void* const* d_in, const int* in_sizes, int n_in,
                              void* d_out, int out_size, void* d_ws, size_t ws_size,
                              hipStream_t stream)
{
    const float* qpos = (const float*)d_in[0];
    const float* pxz  = (const float*)d_in[1];
    const float* pxy  = (const float*)d_in[2];
    const float* pyz  = (const float*)d_in[3];
    const float* cpts = (const float*)d_in[4];
    const float* Wv   = (const float*)d_in[5];
    const float* bv   = (const float*)d_in[6];
    const float* Ww   = (const float*)d_in[7];
    const float* bw   = (const float*)d_in[8];
    const float* Wo   = (const float*)d_in[9];
    const float* bo   = (const float*)d_in[10];
    float* out = (float*)d_out;

    const size_t planeElems = (size_t)BS * C * RR * RR;        // 16,777,216 per plane
    const size_t needed     = 3 * planeElems * sizeof(float);  // ~201 MB

    if (ws_size >= needed) {
        float* t = (float*)d_ws;
        dim3 tb(32, 8, 1);
        dim3 tg(RR * RR / 32, C / 32, 3 * BS);
        hipLaunchKernelGGL(transpose_k, tg, tb, 0, stream, pxz, pxy, pyz, t);
        attn_k<true><<<BS * NS, 128, 0, stream>>>(
            qpos, t, t + planeElems, t + 2 * planeElems,
            cpts, Wv, bv, Ww, bw, Wo, bo, out);
    } else {
        attn_k<false><<<BS * NS, 128, 0, stream>>>(
            qpos, pxz, pxy, pyz,
            cpts, Wv, bv, Ww, bw, Wo, bo, out);
    }
}

// Round 2
// 126.724 us; speedup vs baseline: 2.5206x; 2.5206x over previous
//
#include <hip/hip_runtime.h>
#include <hip/hip_fp16.h>
#include <math.h>

// Problem constants
constexpr int BS  = 8;
constexpr int NS  = 2048;
constexpr int NCP = 8;
constexpr int NH  = 8;
constexpr int C   = 128;
constexpr int HID = 128;
constexpr int RR  = 128;

constexpr int QPB = 8;    // queries per block
constexpr int VEC = 4;    // channels per thread

constexpr size_t PLE = (size_t)BS * RR * RR * C;  // elems per plane-type slab

// ---------------------------------------------------------------------------
// small float4-ish helpers
// ---------------------------------------------------------------------------
struct F4 { float x, y, z, w; };
__device__ __forceinline__ F4 f4add(F4 a, F4 b) {
    return F4{a.x + b.x, a.y + b.y, a.z + b.z, a.w + b.w};
}
__device__ __forceinline__ F4 f4fma(F4 acc, float s, F4 v) {
    return F4{fmaf(s, v.x, acc.x), fmaf(s, v.y, acc.y),
              fmaf(s, v.z, acc.z), fmaf(s, v.w, acc.w)};
}
__device__ __forceinline__ F4 cvt4(int2 r) {
    __half2 h0 = *reinterpret_cast<__half2*>(&r.x);
    __half2 h1 = *reinterpret_cast<__half2*>(&r.y);
    float2 f0 = __half22float2(h0);
    float2 f1 = __half22float2(h1);
    return F4{f0.x, f0.y, f1.x, f1.y};
}

// ---------------------------------------------------------------------------
// Transpose planes (B,C,R,R) fp32 -> fp16 [pl][b][y][x][c]
// ---------------------------------------------------------------------------
__global__ __launch_bounds__(256) void transpose_k(
    const float* __restrict__ pxz, const float* __restrict__ pxy,
    const float* __restrict__ pyz, __half* __restrict__ dst)
{
    const int z  = blockIdx.z;
    const int pl = z >> 3;
    const int b  = z & 7;
    const float* src = (pl == 0 ? pxz : (pl == 1 ? pxy : pyz)) + (size_t)b * C * RR * RR;
    __half* d = dst + (size_t)z * (RR * RR * C);

    __shared__ float tile[32][33];
    const int N  = RR * RR;
    const int n0 = blockIdx.x * 32;
    const int m0 = blockIdx.y * 32;
    const int tx = threadIdx.x, ty = threadIdx.y;

    #pragma unroll
    for (int ii = 0; ii < 4; ++ii)
        tile[ty + ii * 8][tx] = src[(size_t)(m0 + ty + ii * 8) * N + n0 + tx];
    __syncthreads();
    #pragma unroll
    for (int ii = 0; ii < 4; ++ii)
        d[(size_t)(n0 + ty + ii * 8) * C + m0 + tx] = __float2half(tile[tx][ty + ii * 8]);
}

// ---------------------------------------------------------------------------
// Weight prep: Wf = Wv @ Wo (128x128), bf = bv @ Wo (128),
//              Ww2[c][h] = sum_i Ww[c][i*8+h] (128x8), bw2[h] = sum_i bw[i*8+h]
// ---------------------------------------------------------------------------
__global__ __launch_bounds__(128) void prepw_k(
    const float* __restrict__ Wv, const float* __restrict__ bv,
    const float* __restrict__ Ww, const float* __restrict__ bw,
    const float* __restrict__ Wo,
    float* __restrict__ Wf, float* __restrict__ bf,
    float* __restrict__ Ww2, float* __restrict__ bw2)
{
    const int k = blockIdx.x, c = threadIdx.x;
    if (k < 128) {
        float acc = 0.f;
        #pragma unroll 8
        for (int j = 0; j < 128; ++j) acc += Wv[k * 128 + j] * Wo[j * 128 + c];
        Wf[k * 128 + c] = acc;
    } else if (k == 128) {
        float acc = 0.f;
        #pragma unroll 8
        for (int j = 0; j < 128; ++j) acc += bv[j] * Wo[j * 128 + c];
        bf[c] = acc;
    } else {  // k == 129
        float s[NH];
        #pragma unroll
        for (int h = 0; h < NH; ++h) s[h] = 0.f;
        #pragma unroll
        for (int i = 0; i < NCP; ++i)
            #pragma unroll
            for (int h = 0; h < NH; ++h) s[h] += Ww[c * (NCP * NH) + i * NH + h];
        #pragma unroll
        for (int h = 0; h < NH; ++h) Ww2[c * NH + h] = s[h];
        if (c < NH) {
            float t = 0.f;
            #pragma unroll
            for (int i = 0; i < NCP; ++i) t += bw[i * NH + c];
            bw2[c] = t;
        }
    }
}

// ---------------------------------------------------------------------------
// Bilinear sample of 4 fp16 channels; base already offset by batch + c4.
// ---------------------------------------------------------------------------
__device__ __forceinline__ F4 samp(const __half* __restrict__ base, float u, float v)
{
    float x = fminf(fmaxf(u, 0.f), 1.f) * (float)(RR - 1);
    float y = fminf(fmaxf(v, 0.f), 1.f) * (float)(RR - 1);
    float x0f = floorf(x), y0f = floorf(y);
    float wx = x - x0f, wy = y - y0f;
    int x0 = (int)x0f, y0 = (int)y0f;
    int x1 = min(x0 + 1, RR - 1), y1 = min(y0 + 1, RR - 1);
    int r0 = y0 << 14, r1 = y1 << 14, cc0 = x0 << 7, cc1 = x1 << 7;
    int2 a00 = *reinterpret_cast<const int2*>(base + r0 + cc0);
    int2 a01 = *reinterpret_cast<const int2*>(base + r0 + cc1);
    int2 a10 = *reinterpret_cast<const int2*>(base + r1 + cc0);
    int2 a11 = *reinterpret_cast<const int2*>(base + r1 + cc1);
    float w00 = (1.f - wx) * (1.f - wy), w01 = wx * (1.f - wy);
    float w10 = (1.f - wx) * wy,         w11 = wx * wy;
    F4 f00 = cvt4(a00), f01 = cvt4(a01), f10 = cvt4(a10), f11 = cvt4(a11);
    F4 r;
    r.x = f00.x * w00 + f01.x * w01 + f10.x * w10 + f11.x * w11;
    r.y = f00.y * w00 + f01.y * w01 + f10.y * w10 + f11.y * w11;
    r.z = f00.z * w00 + f01.z * w01 + f10.z * w10 + f11.z * w11;
    r.w = f00.w * w00 + f01.w * w01 + f10.w * w10 + f11.w * w11;
    return r;
}

// ---------------------------------------------------------------------------
// Main fused kernel: 256 threads = 8 queries x 32 threads (4 channels each).
// ---------------------------------------------------------------------------
__global__ __launch_bounds__(256) void attn_k(
    const float* __restrict__ qpos,
    const __half* __restrict__ planes,   // [3][B][R][R][C] fp16
    const float* __restrict__ cpts,
    const float* __restrict__ Ww2, const float* __restrict__ bw2,
    const float* __restrict__ Wf,  const float* __restrict__ bf,
    const float* __restrict__ bo,
    float* __restrict__ out)
{
    // XCD-aware swizzle (gridDim.x = 2048, divisible by 8): each XCD gets a
    // contiguous chunk of queries -> one batch's planes per XCD L2.
    const int nb   = gridDim.x;
    const int cpx  = nb >> 3;
    const int sbid = (blockIdx.x & 7) * cpx + (blockIdx.x >> 3);

    const int tid  = threadIdx.x;
    const int ql   = tid >> 5;
    const int lane = tid & 31;
    const int c4   = lane * VEC;
    const int q    = sbid * QPB + ql;
    const int b    = q >> 11;          // q / NS

    const float* qp = qpos + (size_t)q * 9;
    const float px = qp[0], py = qp[1], pz = qp[2];
    const float a1x = qp[3], a1y = qp[4], a1z = qp[5];
    const float a2x = qp[6], a2y = qp[7], a2z = qp[8];

    float inv = 1.f / sqrtf(a1x * a1x + a1y * a1y + a1z * a1z);
    float b1x = a1x * inv, b1y = a1y * inv, b1z = a1z * inv;
    float dd  = b1x * a2x + b1y * a2y + b1z * a2z;
    float b2x = a2x - dd * b1x, b2y = a2y - dd * b1y, b2z = a2z - dd * b1z;
    inv = 1.f / sqrtf(b2x * b2x + b2y * b2y + b2z * b2z);
    b2x *= inv; b2y *= inv; b2z *= inv;
    float b3x = b1y * b2z - b1z * b2y;
    float b3y = b1z * b2x - b1x * b2z;
    float b3z = b1x * b2y - b1y * b2x;

    const __half* Pxz = planes + (size_t)b * (RR * RR * C) + c4;
    const __half* Pxy = Pxz + PLE;
    const __half* Pyz = Pxy + PLE;

    // ---- pass 1: base feature (4 channels) ----
    F4 feat = f4add(f4add(samp(Pxz, px, pz), samp(Pxy, px, py)), samp(Pyz, py, pz));

    // ---- ws[h] = feat . Ww2[:,h] + bw2[h], reduced over the 32-lane group ----
    float p[NH];
    #pragma unroll
    for (int h = 0; h < NH; ++h) p[h] = 0.f;
    {
        const float* wr = Ww2 + c4 * NH;
        const float fv[VEC] = {feat.x, feat.y, feat.z, feat.w};
        #pragma unroll
        for (int i = 0; i < VEC; ++i)
            #pragma unroll
            for (int h = 0; h < NH; ++h) p[h] += fv[i] * wr[i * NH + h];
    }
    #pragma unroll
    for (int off = 16; off >= 1; off >>= 1)
        #pragma unroll
        for (int h = 0; h < NH; ++h) p[h] += __shfl_xor(p[h], off);

    float ws[NH], Ssum = 0.f;
    #pragma unroll
    for (int h = 0; h < NH; ++h) { ws[h] = p[h] + bw2[h]; Ssum += ws[h]; }

    // ---- pass 2: anchors, accumulate comb = sum_g ws[g]*sf[g] ----
    F4 comb = {0.f, 0.f, 0.f, 0.f};
    #pragma unroll 2
    for (int g = 0; g < NCP; ++g) {
        float cx = cpts[g * 3 + 0], cy = cpts[g * 3 + 1], cz = cpts[g * 3 + 2];
        float ax = px + b1x * cx + b1y * cy + b1z * cz;
        float ay = py + b2x * cx + b2y * cy + b2z * cz;
        float az = pz + b3x * cx + b3y * cy + b3z * cz;
        F4 s = f4add(f4add(samp(Pxz, ax, az), samp(Pxy, ax, ay)), samp(Pyz, ay, az));
        comb = f4fma(comb, ws[g], s);
    }

    // ---- stash per-query vectors ----
    __shared__ float sComb[QPB][C];
    __shared__ float sFeat[QPB][C];
    __shared__ float sSum[QPB];
    *reinterpret_cast<float4*>(&sComb[ql][c4]) = make_float4(comb.x, comb.y, comb.z, comb.w);
    *reinterpret_cast<float4*>(&sFeat[ql][c4]) = make_float4(feat.x, feat.y, feat.z, feat.w);
    if (lane == 0) sSum[ql] = Ssum;
    __syncthreads();

    // ---- epilogue GEMV: out[c] = comb.Wf[:,c] + Ssum*bf[c] + bo[c] + feat[c] ----
    const int c  = tid & 127;
    const int q0 = (tid >> 7) * 4;   // queries q0..q0+3
    float acc[4];
    const float bfc = bf[c], boc = bo[c];
    #pragma unroll
    for (int j = 0; j < 4; ++j)
        acc[j] = sSum[q0 + j] * bfc + boc + sFeat[q0 + j][c];
    #pragma unroll 4
    for (int k = 0; k < C; ++k) {
        float wf = Wf[k * C + c];
        #pragma unroll
        for (int j = 0; j < 4; ++j) acc[j] += sComb[q0 + j][k] * wf;
    }
    #pragma unroll
    for (int j = 0; j < 4; ++j)
        out[(size_t)(sbid * QPB + q0 + j) * C + c] = acc[j];
}

// ---------------------------------------------------------------------------
extern "C" void kernel_launch(void* const* d_in, const int* in_sizes, int n_in,
                              void* d_out, int out_size, void* d_ws, size_t ws_size,
                              hipStream_t stream)
{
    const float* qpos = (const float*)d_in[0];
    const float* pxz  = (const float*)d_in[1];
    const float* pxy  = (const float*)d_in[2];
    const float* pyz  = (const float*)d_in[3];
    const float* cpts = (const float*)d_in[4];
    const float* Wv   = (const float*)d_in[5];
    const float* bv   = (const float*)d_in[6];
    const float* Ww   = (const float*)d_in[7];
    const float* bw   = (const float*)d_in[8];
    const float* Wo   = (const float*)d_in[9];
    const float* bo   = (const float*)d_in[10];
    float* out = (float*)d_out;

    __half* plh = (__half*)d_ws;
    float*  wsf = (float*)((char*)d_ws + 3 * PLE * sizeof(__half));  // ~96 MB in
    float* Wf  = wsf;                 // 128*128
    float* bf  = Wf + C * HID;        // 128
    float* Ww2 = bf + C;              // 128*8
    float* bw2 = Ww2 + C * NH;        // 8

    // transpose planes to fp16 channel-last
    {
        dim3 tb(32, 8, 1);
        dim3 tg(RR * RR / 32, C / 32, 3 * BS);
        hipLaunchKernelGGL(transpose_k, tg, tb, 0, stream, pxz, pxy, pyz, plh);
    }
    // weight prep
    hipLaunchKernelGGL(prepw_k, dim3(130), dim3(128), 0, stream,
                       Wv, bv, Ww, bw, Wo, Wf, bf, Ww2, bw2);
    // fused main kernel
    hipLaunchKernelGGL(attn_k, dim3(BS * NS / QPB), dim3(256), 0, stream,
                       qpos, plh, cpts, Ww2, bw2, Wf, bf, bo, out);
}

// Round 3
// 121.232 us; speedup vs baseline: 2.6348x; 1.0453x over previous
//
#include <hip/hip_runtime.h>
#include <hip/hip_fp16.h>
#include <math.h>

// Problem constants
constexpr int BS  = 8;
constexpr int NS  = 2048;
constexpr int NCP = 8;
constexpr int NH  = 8;
constexpr int C   = 128;
constexpr int HID = 128;
constexpr int RR  = 128;

constexpr int QPB = 8;    // queries per block (attn)
constexpr int VEC = 4;    // channels per thread (attn)

constexpr int NPOS = RR * RR;                       // 16384 positions per slab
constexpr size_t PLE = (size_t)BS * NPOS * C;       // elems per plane-type slab

// transpose geometry: 64 positions x all 128 channels per block
constexpr int TPOS   = 64;
constexpr int NBLK_T = 3 * BS * (NPOS / TPOS);      // 6144
constexpr int LDSP   = 132;                          // halves per LDS row (pad +4)

// ---------------------------------------------------------------------------
struct F4 { float x, y, z, w; };
__device__ __forceinline__ F4 f4add(F4 a, F4 b) {
    return F4{a.x + b.x, a.y + b.y, a.z + b.z, a.w + b.w};
}
__device__ __forceinline__ F4 f4fma(F4 acc, float s, F4 v) {
    return F4{fmaf(s, v.x, acc.x), fmaf(s, v.y, acc.y),
              fmaf(s, v.z, acc.z), fmaf(s, v.w, acc.w)};
}
__device__ __forceinline__ F4 cvt4(int2 r) {
    __half2 h0 = *reinterpret_cast<__half2*>(&r.x);
    __half2 h1 = *reinterpret_cast<__half2*>(&r.y);
    float2 f0 = __half22float2(h0);
    float2 f1 = __half22float2(h1);
    return F4{f0.x, f0.y, f1.x, f1.y};
}

// ---------------------------------------------------------------------------
// Fused transpose (fp32 [C][R][R] -> fp16 [R*R][C]) + weight prep.
// Blocks [0, 6144): transpose tiles. Blocks [6144, 6274): weight prep.
// ---------------------------------------------------------------------------
__global__ __launch_bounds__(256) void trans_prep_k(
    const float* __restrict__ pxz, const float* __restrict__ pxy,
    const float* __restrict__ pyz, __half* __restrict__ dst,
    const float* __restrict__ Wv, const float* __restrict__ bv,
    const float* __restrict__ Ww, const float* __restrict__ bw,
    const float* __restrict__ Wo,
    float* __restrict__ Wf, float* __restrict__ bf,
    float* __restrict__ Ww2, float* __restrict__ bw2)
{
    const int bid = blockIdx.x;
    const int t   = threadIdx.x;

    if (bid >= NBLK_T) {
        // ----- weight prep -----
        const int k = bid - NBLK_T;
        const int c = t;
        if (c >= 128) return;
        if (k < 128) {
            float acc = 0.f;
            #pragma unroll 8
            for (int j = 0; j < 128; ++j) acc += Wv[k * 128 + j] * Wo[j * 128 + c];
            Wf[k * 128 + c] = acc;
        } else if (k == 128) {
            float acc = 0.f;
            #pragma unroll 8
            for (int j = 0; j < 128; ++j) acc += bv[j] * Wo[j * 128 + c];
            bf[c] = acc;
        } else {  // k == 129
            float s[NH];
            #pragma unroll
            for (int h = 0; h < NH; ++h) s[h] = 0.f;
            #pragma unroll
            for (int i = 0; i < NCP; ++i)
                #pragma unroll
                for (int h = 0; h < NH; ++h) s[h] += Ww[c * (NCP * NH) + i * NH + h];
            #pragma unroll
            for (int h = 0; h < NH; ++h) Ww2[c * NH + h] = s[h];
            if (c < NH) {
                float tt = 0.f;
                #pragma unroll
                for (int i = 0; i < NCP; ++i) tt += bw[i * NH + c];
                bw2[c] = tt;
            }
        }
        return;
    }

    // ----- transpose tile -----
    // XCD-align: batch = bid & 7 so batch b's planes are produced on XCD b.
    const int b   = bid & 7;
    const int idx = bid >> 3;             // 0..767
    const int pl  = idx >> 8;             // 0..2
    const int n0  = (idx & 255) * TPOS;   // position base

    const float* src = (pl == 0 ? pxz : (pl == 1 ? pxy : pyz))
                       + (size_t)b * C * NPOS;
    __half* d = dst + (size_t)(pl * BS + b) * ((size_t)NPOS * C);

    __shared__ __half lds[TPOS * LDSP];

    // load: 128 rows x 64 floats; 16 lanes cover one 256B row segment
    #pragma unroll
    for (int i = 0; i < 8; ++i) {
        int li = i * 256 + t;
        int m  = li >> 4;             // channel 0..127
        int k4 = (li & 15) << 2;      // position offset 0..60
        float4 v = *reinterpret_cast<const float4*>(src + (size_t)m * NPOS + n0 + k4);
        lds[(k4 + 0) * LDSP + m] = __float2half(v.x);
        lds[(k4 + 1) * LDSP + m] = __float2half(v.y);
        lds[(k4 + 2) * LDSP + m] = __float2half(v.z);
        lds[(k4 + 3) * LDSP + m] = __float2half(v.w);
    }
    __syncthreads();

    // store: 64 positions x 128 fp16 channels; 32 lanes cover one 256B row
    #pragma unroll
    for (int i = 0; i < 8; ++i) {
        int li = i * 256 + t;
        int n  = li >> 5;             // position 0..63
        int c4 = (li & 31) << 2;      // channel 0..124
        uint2 v = *reinterpret_cast<const uint2*>(lds + n * LDSP + c4);
        *reinterpret_cast<uint2*>(d + (size_t)(n0 + n) * C + c4) = v;
    }
}

// ---------------------------------------------------------------------------
// Bilinear sample of 4 fp16 channels; base already offset by batch + c4.
// ---------------------------------------------------------------------------
__device__ __forceinline__ F4 samp(const __half* __restrict__ base, float u, float v)
{
    float x = fminf(fmaxf(u, 0.f), 1.f) * (float)(RR - 1);
    float y = fminf(fmaxf(v, 0.f), 1.f) * (float)(RR - 1);
    float x0f = floorf(x), y0f = floorf(y);
    float wx = x - x0f, wy = y - y0f;
    int x0 = (int)x0f, y0 = (int)y0f;
    int x1 = min(x0 + 1, RR - 1), y1 = min(y0 + 1, RR - 1);
    int r0 = y0 << 14, r1 = y1 << 14, cc0 = x0 << 7, cc1 = x1 << 7;
    int2 a00 = *reinterpret_cast<const int2*>(base + r0 + cc0);
    int2 a01 = *reinterpret_cast<const int2*>(base + r0 + cc1);
    int2 a10 = *reinterpret_cast<const int2*>(base + r1 + cc0);
    int2 a11 = *reinterpret_cast<const int2*>(base + r1 + cc1);
    float w00 = (1.f - wx) * (1.f - wy), w01 = wx * (1.f - wy);
    float w10 = (1.f - wx) * wy,         w11 = wx * wy;
    F4 f00 = cvt4(a00), f01 = cvt4(a01), f10 = cvt4(a10), f11 = cvt4(a11);
    F4 r;
    r.x = f00.x * w00 + f01.x * w01 + f10.x * w10 + f11.x * w11;
    r.y = f00.y * w00 + f01.y * w01 + f10.y * w10 + f11.y * w11;
    r.z = f00.z * w00 + f01.z * w01 + f10.z * w10 + f11.z * w11;
    r.w = f00.w * w00 + f01.w * w01 + f10.w * w10 + f11.w * w11;
    return r;
}

// ---------------------------------------------------------------------------
// Main fused kernel: 256 threads = 8 queries x 32 threads (4 channels each).
// ---------------------------------------------------------------------------
__global__ __launch_bounds__(256) void attn_k(
    const float* __restrict__ qpos,
    const __half* __restrict__ planes,   // [3][B][R][R][C] fp16
    const float* __restrict__ cpts,
    const float* __restrict__ Ww2, const float* __restrict__ bw2,
    const float* __restrict__ Wf,  const float* __restrict__ bf,
    const float* __restrict__ bo,
    float* __restrict__ out)
{
    // XCD-aware swizzle (gridDim.x = 2048, divisible by 8)
    const int nb   = gridDim.x;
    const int cpx  = nb >> 3;
    const int sbid = (blockIdx.x & 7) * cpx + (blockIdx.x >> 3);

    const int tid  = threadIdx.x;
    const int ql   = tid >> 5;
    const int lane = tid & 31;
    const int c4   = lane * VEC;
    const int q    = sbid * QPB + ql;
    const int b    = q >> 11;          // q / NS

    const float* qp = qpos + (size_t)q * 9;
    const float px = qp[0], py = qp[1], pz = qp[2];
    const float a1x = qp[3], a1y = qp[4], a1z = qp[5];
    const float a2x = qp[6], a2y = qp[7], a2z = qp[8];

    float inv = 1.f / sqrtf(a1x * a1x + a1y * a1y + a1z * a1z);
    float b1x = a1x * inv, b1y = a1y * inv, b1z = a1z * inv;
    float dd  = b1x * a2x + b1y * a2y + b1z * a2z;
    float b2x = a2x - dd * b1x, b2y = a2y - dd * b1y, b2z = a2z - dd * b1z;
    inv = 1.f / sqrtf(b2x * b2x + b2y * b2y + b2z * b2z);
    b2x *= inv; b2y *= inv; b2z *= inv;
    float b3x = b1y * b2z - b1z * b2y;
    float b3y = b1z * b2x - b1x * b2z;
    float b3z = b1x * b2y - b1y * b2x;

    const __half* Pxz = planes + (size_t)b * ((size_t)NPOS * C) + c4;
    const __half* Pxy = Pxz + PLE;
    const __half* Pyz = Pxy + PLE;

    // ---- pass 1: base feature (4 channels) ----
    F4 feat = f4add(f4add(samp(Pxz, px, pz), samp(Pxy, px, py)), samp(Pyz, py, pz));

    // ---- ws[h] = feat . Ww2[:,h] + bw2[h], reduced over the 32-lane group ----
    float p[NH];
    #pragma unroll
    for (int h = 0; h < NH; ++h) p[h] = 0.f;
    {
        const float* wr = Ww2 + c4 * NH;
        const float fv[VEC] = {feat.x, feat.y, feat.z, feat.w};
        #pragma unroll
        for (int i = 0; i < VEC; ++i)
            #pragma unroll
            for (int h = 0; h < NH; ++h) p[h] += fv[i] * wr[i * NH + h];
    }
    #pragma unroll
    for (int off = 16; off >= 1; off >>= 1)
        #pragma unroll
        for (int h = 0; h < NH; ++h) p[h] += __shfl_xor(p[h], off);

    float ws[NH], Ssum = 0.f;
    #pragma unroll
    for (int h = 0; h < NH; ++h) { ws[h] = p[h] + bw2[h]; Ssum += ws[h]; }

    // ---- pass 2: anchors, accumulate comb = sum_g ws[g]*sf[g] ----
    F4 comb = {0.f, 0.f, 0.f, 0.f};
    #pragma unroll 2
    for (int g = 0; g < NCP; ++g) {
        float cx = cpts[g * 3 + 0], cy = cpts[g * 3 + 1], cz = cpts[g * 3 + 2];
        float ax = px + b1x * cx + b1y * cy + b1z * cz;
        float ay = py + b2x * cx + b2y * cy + b2z * cz;
        float az = pz + b3x * cx + b3y * cy + b3z * cz;
        F4 s = f4add(f4add(samp(Pxz, ax, az), samp(Pxy, ax, ay)), samp(Pyz, ay, az));
        comb = f4fma(comb, ws[g], s);
    }

    // ---- stash per-query vectors ----
    __shared__ float sComb[QPB][C];
    __shared__ float sFeat[QPB][C];
    __shared__ float sSum[QPB];
    *reinterpret_cast<float4*>(&sComb[ql][c4]) = make_float4(comb.x, comb.y, comb.z, comb.w);
    *reinterpret_cast<float4*>(&sFeat[ql][c4]) = make_float4(feat.x, feat.y, feat.z, feat.w);
    if (lane == 0) sSum[ql] = Ssum;
    __syncthreads();

    // ---- epilogue GEMV: out[c] = comb.Wf[:,c] + Ssum*bf[c] + bo[c] + feat[c] ----
    const int c  = tid & 127;
    const int q0 = (tid >> 7) * 4;   // queries q0..q0+3
    float acc[4];
    const float bfc = bf[c], boc = bo[c];
    #pragma unroll
    for (int j = 0; j < 4; ++j)
        acc[j] = sSum[q0 + j] * bfc + boc + sFeat[q0 + j][c];
    #pragma unroll 4
    for (int k = 0; k < C; ++k) {
        float wf = Wf[k * C + c];
        #pragma unroll
        for (int j = 0; j < 4; ++j) acc[j] += sComb[q0 + j][k] * wf;
    }
    #pragma unroll
    for (int j = 0; j < 4; ++j)
        out[(size_t)(sbid * QPB + q0 + j) * C + c] = acc[j];
}

// ---------------------------------------------------------------------------
extern "C" void kernel_launch(void* const* d_in, const int* in_sizes, int n_in,
                              void* d_out, int out_size, void* d_ws, size_t ws_size,
                              hipStream_t stream)
{
    const float* qpos = (const float*)d_in[0];
    const float* pxz  = (const float*)d_in[1];
    const float* pxy  = (const float*)d_in[2];
    const float* pyz  = (const float*)d_in[3];
    const float* cpts = (const float*)d_in[4];
    const float* Wv   = (const float*)d_in[5];
    const float* bv   = (const float*)d_in[6];
    const float* Ww   = (const float*)d_in[7];
    const float* bw   = (const float*)d_in[8];
    const float* Wo   = (const float*)d_in[9];
    const float* bo   = (const float*)d_in[10];
    float* out = (float*)d_out;

    __half* plh = (__half*)d_ws;
    float*  wsf = (float*)((char*)d_ws + 3 * PLE * sizeof(__half));  // ~96 MB in
    float* Wf  = wsf;                 // 128*128
    float* bf  = Wf + C * HID;        // 128
    float* Ww2 = bf + C;              // 128*8
    float* bw2 = Ww2 + C * NH;        // 8

    // fused transpose + weight prep
    hipLaunchKernelGGL(trans_prep_k, dim3(NBLK_T + 130), dim3(256), 0, stream,
                       pxz, pxy, pyz, plh, Wv, bv, Ww, bw, Wo, Wf, bf, Ww2, bw2);

    // fused main kernel
    hipLaunchKernelGGL(attn_k, dim3(BS * NS / QPB), dim3(256), 0, stream,
                       qpos, plh, cpts, Ww2, bw2, Wf, bf, bo, out);
}

// Round 4
// 120.206 us; speedup vs baseline: 2.6572x; 1.0085x over previous
//
#include <hip/hip_runtime.h>
#include <hip/hip_fp16.h>
#include <math.h>

// Problem constants
constexpr int BS  = 8;
constexpr int NS  = 2048;
constexpr int NCP = 8;
constexpr int NH  = 8;
constexpr int C   = 128;
constexpr int HID = 128;
constexpr int RR  = 128;

constexpr int QPB = 8;    // queries per block (attn)
constexpr int VEC = 4;    // channels per thread (attn)

constexpr int NPOS = RR * RR;                       // 16384 positions per slab
constexpr size_t PLE = (size_t)BS * NPOS * C;       // elems per plane-type slab

// transpose geometry: 128 positions (one full x-row) x all 128 channels
constexpr int TPOS   = 128;
constexpr int NBLK_T = 3 * BS * (NPOS / TPOS);      // 3072
constexpr int LDSP   = 130;                          // halves per position row

// ---------------------------------------------------------------------------
struct F4 { float x, y, z, w; };
__device__ __forceinline__ F4 f4add(F4 a, F4 b) {
    return F4{a.x + b.x, a.y + b.y, a.z + b.z, a.w + b.w};
}
__device__ __forceinline__ F4 f4fma(F4 acc, float s, F4 v) {
    return F4{fmaf(s, v.x, acc.x), fmaf(s, v.y, acc.y),
              fmaf(s, v.z, acc.z), fmaf(s, v.w, acc.w)};
}
__device__ __forceinline__ F4 cvt4(int2 r) {
    __half2 h0 = *reinterpret_cast<__half2*>(&r.x);
    __half2 h1 = *reinterpret_cast<__half2*>(&r.y);
    float2 f0 = __half22float2(h0);
    float2 f1 = __half22float2(h1);
    return F4{f0.x, f0.y, f1.x, f1.y};
}

// ---------------------------------------------------------------------------
// Fused transpose (fp32 [C][R][R] -> fp16 [R*R][C]) + weight prep.
// Blocks [0, 3072): transpose tiles. Blocks [3072, 3202): weight prep.
// ---------------------------------------------------------------------------
__global__ __launch_bounds__(256, 4) void trans_prep_k(
    const float* __restrict__ pxz, const float* __restrict__ pxy,
    const float* __restrict__ pyz, __half* __restrict__ dst,
    const float* __restrict__ Wv, const float* __restrict__ bv,
    const float* __restrict__ Ww, const float* __restrict__ bw,
    const float* __restrict__ Wo,
    float* __restrict__ Wf, float* __restrict__ bf,
    float* __restrict__ Ww2, float* __restrict__ bw2)
{
    const int bid = blockIdx.x;
    const int t   = threadIdx.x;

    if (bid >= NBLK_T) {
        // ----- weight prep -----
        const int k = bid - NBLK_T;
        const int c = t;
        if (c >= 128) return;
        if (k < 128) {
            float acc = 0.f;
            #pragma unroll 8
            for (int j = 0; j < 128; ++j) acc += Wv[k * 128 + j] * Wo[j * 128 + c];
            Wf[k * 128 + c] = acc;
        } else if (k == 128) {
            float acc = 0.f;
            #pragma unroll 8
            for (int j = 0; j < 128; ++j) acc += bv[j] * Wo[j * 128 + c];
            bf[c] = acc;
        } else {  // k == 129
            float s[NH];
            #pragma unroll
            for (int h = 0; h < NH; ++h) s[h] = 0.f;
            #pragma unroll
            for (int i = 0; i < NCP; ++i)
                #pragma unroll
                for (int h = 0; h < NH; ++h) s[h] += Ww[c * (NCP * NH) + i * NH + h];
            #pragma unroll
            for (int h = 0; h < NH; ++h) Ww2[c * NH + h] = s[h];
            if (c < NH) {
                float tt = 0.f;
                #pragma unroll
                for (int i = 0; i < NCP; ++i) tt += bw[i * NH + c];
                bw2[c] = tt;
            }
        }
        return;
    }

    // ----- transpose tile: 128 channels x 128 positions -----
    // XCD-align: batch = bid & 7 so batch b's planes are produced on XCD b.
    const int b   = bid & 7;
    const int idx = bid >> 3;             // 0..383
    const int pl  = idx >> 7;             // 0..2
    const int n0  = (idx & 127) << 7;     // position base (full x-row)

    const float* src = (pl == 0 ? pxz : (pl == 1 ? pxy : pyz))
                       + (size_t)b * C * NPOS;
    __half* d = dst + (size_t)(pl * BS + b) * ((size_t)NPOS * C);

    __shared__ __half lds[TPOS * LDSP];

    // Phase A: stage 16 independent float4 loads per thread (deep MLP).
    // 32 lanes cover one 512B channel-row chunk: m = channel, p4 = pos offset.
    float4 ld[16];
    #pragma unroll
    for (int i = 0; i < 16; ++i) {
        int li = i * 256 + t;
        int m  = li >> 5;                 // channel 0..127
        int p4 = (li & 31) << 2;          // position 0..124
        ld[i] = *reinterpret_cast<const float4*>(src + (size_t)m * NPOS + n0 + p4);
    }

    // Phase B: convert + LDS write ([pos][chan], LDSP=130)
    #pragma unroll
    for (int i = 0; i < 16; ++i) {
        int li = i * 256 + t;
        int m  = li >> 5;
        int p4 = (li & 31) << 2;
        lds[(p4 + 0) * LDSP + m] = __float2half(ld[i].x);
        lds[(p4 + 1) * LDSP + m] = __float2half(ld[i].y);
        lds[(p4 + 2) * LDSP + m] = __float2half(ld[i].z);
        lds[(p4 + 3) * LDSP + m] = __float2half(ld[i].w);
    }
    __syncthreads();

    // Phase C: vector LDS reads + 16B coalesced global stores.
    // 16 lanes cover one 256B position row (8 channels each).
    #pragma unroll
    for (int i = 0; i < 8; ++i) {
        int li = i * 256 + t;
        int n  = li >> 4;                 // position 0..127
        int c8 = (li & 15) << 3;          // channel 0..120
        const __half* lp = lds + n * LDSP + c8;
        uint4 v;
        v.x = *reinterpret_cast<const unsigned*>(lp + 0);
        v.y = *reinterpret_cast<const unsigned*>(lp + 2);
        v.z = *reinterpret_cast<const unsigned*>(lp + 4);
        v.w = *reinterpret_cast<const unsigned*>(lp + 6);
        *reinterpret_cast<uint4*>(d + (size_t)(n0 + n) * C + c8) = v;
    }
}

// ---------------------------------------------------------------------------
// Bilinear sample of 4 fp16 channels; base already offset by batch + c4.
// ---------------------------------------------------------------------------
__device__ __forceinline__ F4 samp(const __half* __restrict__ base, float u, float v)
{
    float x = fminf(fmaxf(u, 0.f), 1.f) * (float)(RR - 1);
    float y = fminf(fmaxf(v, 0.f), 1.f) * (float)(RR - 1);
    float x0f = floorf(x), y0f = floorf(y);
    float wx = x - x0f, wy = y - y0f;
    int x0 = (int)x0f, y0 = (int)y0f;
    int x1 = min(x0 + 1, RR - 1), y1 = min(y0 + 1, RR - 1);
    int r0 = y0 << 14, r1 = y1 << 14, cc0 = x0 << 7, cc1 = x1 << 7;
    int2 a00 = *reinterpret_cast<const int2*>(base + r0 + cc0);
    int2 a01 = *reinterpret_cast<const int2*>(base + r0 + cc1);
    int2 a10 = *reinterpret_cast<const int2*>(base + r1 + cc0);
    int2 a11 = *reinterpret_cast<const int2*>(base + r1 + cc1);
    float w00 = (1.f - wx) * (1.f - wy), w01 = wx * (1.f - wy);
    float w10 = (1.f - wx) * wy,         w11 = wx * wy;
    F4 f00 = cvt4(a00), f01 = cvt4(a01), f10 = cvt4(a10), f11 = cvt4(a11);
    F4 r;
    r.x = f00.x * w00 + f01.x * w01 + f10.x * w10 + f11.x * w11;
    r.y = f00.y * w00 + f01.y * w01 + f10.y * w10 + f11.y * w11;
    r.z = f00.z * w00 + f01.z * w01 + f10.z * w10 + f11.z * w11;
    r.w = f00.w * w00 + f01.w * w01 + f10.w * w10 + f11.w * w11;
    return r;
}

// ---------------------------------------------------------------------------
// Main fused kernel: 256 threads = 8 queries x 32 threads (4 channels each).
// ---------------------------------------------------------------------------
__global__ __launch_bounds__(256) void attn_k(
    const float* __restrict__ qpos,
    const __half* __restrict__ planes,   // [3][B][R][R][C] fp16
    const float* __restrict__ cpts,
    const float* __restrict__ Ww2, const float* __restrict__ bw2,
    const float* __restrict__ Wf,  const float* __restrict__ bf,
    const float* __restrict__ bo,
    float* __restrict__ out)
{
    // XCD-aware swizzle (gridDim.x = 2048, divisible by 8)
    const int nb   = gridDim.x;
    const int cpx  = nb >> 3;
    const int sbid = (blockIdx.x & 7) * cpx + (blockIdx.x >> 3);

    const int tid  = threadIdx.x;
    const int ql   = tid >> 5;
    const int lane = tid & 31;
    const int c4   = lane * VEC;
    const int q    = sbid * QPB + ql;
    const int b    = q >> 11;          // q / NS

    const float* qp = qpos + (size_t)q * 9;
    const float px = qp[0], py = qp[1], pz = qp[2];
    const float a1x = qp[3], a1y = qp[4], a1z = qp[5];
    const float a2x = qp[6], a2y = qp[7], a2z = qp[8];

    float inv = 1.f / sqrtf(a1x * a1x + a1y * a1y + a1z * a1z);
    float b1x = a1x * inv, b1y = a1y * inv, b1z = a1z * inv;
    float dd  = b1x * a2x + b1y * a2y + b1z * a2z;
    float b2x = a2x - dd * b1x, b2y = a2y - dd * b1y, b2z = a2z - dd * b1z;
    inv = 1.f / sqrtf(b2x * b2x + b2y * b2y + b2z * b2z);
    b2x *= inv; b2y *= inv; b2z *= inv;
    float b3x = b1y * b2z - b1z * b2y;
    float b3y = b1z * b2x - b1x * b2z;
    float b3z = b1x * b2y - b1y * b2x;

    const __half* Pxz = planes + (size_t)b * ((size_t)NPOS * C) + c4;
    const __half* Pxy = Pxz + PLE;
    const __half* Pyz = Pxy + PLE;

    // ---- pass 1: base feature (4 channels) ----
    F4 feat = f4add(f4add(samp(Pxz, px, pz), samp(Pxy, px, py)), samp(Pyz, py, pz));

    // ---- ws[h] = feat . Ww2[:,h] + bw2[h], reduced over the 32-lane group ----
    float p[NH];
    #pragma unroll
    for (int h = 0; h < NH; ++h) p[h] = 0.f;
    {
        const float* wr = Ww2 + c4 * NH;
        const float fv[VEC] = {feat.x, feat.y, feat.z, feat.w};
        #pragma unroll
        for (int i = 0; i < VEC; ++i)
            #pragma unroll
            for (int h = 0; h < NH; ++h) p[h] += fv[i] * wr[i * NH + h];
    }
    #pragma unroll
    for (int off = 16; off >= 1; off >>= 1)
        #pragma unroll
        for (int h = 0; h < NH; ++h) p[h] += __shfl_xor(p[h], off);

    float ws[NH], Ssum = 0.f;
    #pragma unroll
    for (int h = 0; h < NH; ++h) { ws[h] = p[h] + bw2[h]; Ssum += ws[h]; }

    // ---- pass 2: anchors, accumulate comb = sum_g ws[g]*sf[g] ----
    F4 comb = {0.f, 0.f, 0.f, 0.f};
    #pragma unroll 2
    for (int g = 0; g < NCP; ++g) {
        float cx = cpts[g * 3 + 0], cy = cpts[g * 3 + 1], cz = cpts[g * 3 + 2];
        float ax = px + b1x * cx + b1y * cy + b1z * cz;
        float ay = py + b2x * cx + b2y * cy + b2z * cz;
        float az = pz + b3x * cx + b3y * cy + b3z * cz;
        F4 s = f4add(f4add(samp(Pxz, ax, az), samp(Pxy, ax, ay)), samp(Pyz, ay, az));
        comb = f4fma(comb, ws[g], s);
    }

    // ---- stash per-query vectors ----
    __shared__ float sComb[QPB][C];
    __shared__ float sFeat[QPB][C];
    __shared__ float sSum[QPB];
    *reinterpret_cast<float4*>(&sComb[ql][c4]) = make_float4(comb.x, comb.y, comb.z, comb.w);
    *reinterpret_cast<float4*>(&sFeat[ql][c4]) = make_float4(feat.x, feat.y, feat.z, feat.w);
    if (lane == 0) sSum[ql] = Ssum;
    __syncthreads();

    // ---- epilogue GEMV: out[c] = comb.Wf[:,c] + Ssum*bf[c] + bo[c] + feat[c] ----
    const int c  = tid & 127;
    const int q0 = (tid >> 7) * 4;   // queries q0..q0+3
    float acc[4];
    const float bfc = bf[c], boc = bo[c];
    #pragma unroll
    for (int j = 0; j < 4; ++j)
        acc[j] = sSum[q0 + j] * bfc + boc + sFeat[q0 + j][c];
    #pragma unroll 4
    for (int k = 0; k < C; ++k) {
        float wf = Wf[k * C + c];
        #pragma unroll
        for (int j = 0; j < 4; ++j) acc[j] += sComb[q0 + j][k] * wf;
    }
    #pragma unroll
    for (int j = 0; j < 4; ++j)
        out[(size_t)(sbid * QPB + q0 + j) * C + c] = acc[j];
}

// ---------------------------------------------------------------------------
extern "C" void kernel_launch(void* const* d_in, const int* in_sizes, int n_in,
                              void* d_out, int out_size, void* d_ws, size_t ws_size,
                              hipStream_t stream)
{
    const float* qpos = (const float*)d_in[0];
    const float* pxz  = (const float*)d_in[1];
    const float* pxy  = (const float*)d_in[2];
    const float* pyz  = (const float*)d_in[3];
    const float* cpts = (const float*)d_in[4];
    const float* Wv   = (const float*)d_in[5];
    const float* bv   = (const float*)d_in[6];
    const float* Ww   = (const float*)d_in[7];
    const float* bw   = (const float*)d_in[8];
    const float* Wo   = (const float*)d_in[9];
    const float* bo   = (const float*)d_in[10];
    float* out = (float*)d_out;

    __half* plh = (__half*)d_ws;
    float*  wsf = (float*)((char*)d_ws + 3 * PLE * sizeof(__half));  // ~96 MB in
    float* Wf  = wsf;                 // 128*128
    float* bf  = Wf + C * HID;        // 128
    float* Ww2 = bf + C;              // 128*8
    float* bw2 = Ww2 + C * NH;        // 8

    // fused transpose + weight prep
    hipLaunchKernelGGL(trans_prep_k, dim3(NBLK_T + 130), dim3(256), 0, stream,
                       pxz, pxy, pyz, plh, Wv, bv, Ww, bw, Wo, Wf, bf, Ww2, bw2);

    // fused main kernel
    hipLaunchKernelGGL(attn_k, dim3(BS * NS / QPB), dim3(256), 0, stream,
                       qpos, plh, cpts, Ww2, bw2, Wf, bf, bo, out);
}